// Round 3
// baseline (494.318 us; speedup 1.0000x reference)
//
#include <hip/hip_runtime.h>
#include <math.h>

#define HW 4096
#define NB 32
#define VD 16

// ws layout (float offsets) — no zero-init required anywhere
#define OFF_M0P   0        // 32 batches * 16 blocks * 16 ch  = 8192 per-block partial sums
#define OFF_MSP   8192     // 32 batches * 8 blocks           = 256 per-block mantissa sums
#define OFF_M     8448     // 32*256 composed path matrices
#define OFF_C     16640    // 32*16  composed path biases
#define OFF_P0    17152    // 32*16*4096 partial feats0 (ch 0..255, + bias)
#define OFF_P1    2114304  // 32*16*4096 partial feats0 (ch 256..511)

// Root conv, channel-split in 2: each block reduces 256 channels for 512 pixels.
// Weights read directly from root_w via wave-uniform scalar loads (s_load).
// Per-block channel sums go to unique slots (no atomics, no memset).
__global__ __launch_bounds__(128) void k_root(const float* __restrict__ feat,
                                              const float* __restrict__ rw,
                                              const float* __restrict__ rb,
                                              float* __restrict__ pbase,
                                              float* __restrict__ m0p) {
    const int b  = blockIdx.y;
    const int s  = blockIdx.z;                       // channel half
    const int bx = blockIdx.x;
    const int px = bx * 512 + threadIdx.x * 4;
    const int cb = s * 256;
    const float* fp = feat + (size_t)b * 512 * HW + (size_t)cb * HW + px;

    float4 acc[VD];
#pragma unroll
    for (int o = 0; o < VD; ++o) {
        float bb = (s == 0) ? rb[o] : 0.0f;
        acc[o].x = bb; acc[o].y = bb; acc[o].z = bb; acc[o].w = bb;
    }

    for (int c = 0; c < 256; c += 4) {
        float4 f0 = *(const float4*)(fp + (size_t)(c + 0) * HW);
        float4 f1 = *(const float4*)(fp + (size_t)(c + 1) * HW);
        float4 f2 = *(const float4*)(fp + (size_t)(c + 2) * HW);
        float4 f3 = *(const float4*)(fp + (size_t)(c + 3) * HW);
#pragma unroll
        for (int o = 0; o < VD; ++o) {
            const float* wr = rw + o * 512 + cb + c;   // wave-uniform -> s_load_dwordx4
            float w0 = wr[0], w1 = wr[1], w2 = wr[2], w3 = wr[3];
            acc[o].x += w0 * f0.x + w1 * f1.x + w2 * f2.x + w3 * f3.x;
            acc[o].y += w0 * f0.y + w1 * f1.y + w2 * f2.y + w3 * f3.y;
            acc[o].z += w0 * f0.z + w1 * f1.z + w2 * f2.z + w3 * f3.z;
            acc[o].w += w0 * f0.w + w1 * f1.w + w2 * f2.w + w3 * f3.w;
        }
    }

    float* op = pbase + (size_t)s * 2097152 + (size_t)b * VD * HW + px;
#pragma unroll
    for (int o = 0; o < VD; ++o) *(float4*)(op + (size_t)o * HW) = acc[o];

    __shared__ float red[2][VD];
    const int lane = threadIdx.x & 63, wv = threadIdx.x >> 6;
#pragma unroll
    for (int o = 0; o < VD; ++o) {
        float v = acc[o].x + acc[o].y + acc[o].z + acc[o].w;
#pragma unroll
        for (int off = 32; off > 0; off >>= 1) v += __shfl_down(v, off);
        if (lane == 0) red[wv][o] = v;
    }
    __syncthreads();
    if (threadIdx.x < VD)
        m0p[(b * 16 + s * 8 + bx) * VD + threadIdx.x] = red[0][threadIdx.x] + red[1][threadIdx.x];
}

// Tree walk on means: class_logits, selected_class, composed affine map (M,c) per batch.
__global__ __launch_bounds__(64) void k_tree(const float* __restrict__ lw,
                                             const float* __restrict__ lb,
                                             float* __restrict__ ws,
                                             float* __restrict__ out) {
    const int b = blockIdx.x;
    const int t = threadIdx.x;
    __shared__ float lm[15][VD];       // means: levels 0..4, row offsets 0,1,3,6,10
    __shared__ float Wst[256];
    __shared__ int   path[5];
    const int Soff[5] = {0, 1, 3, 6, 10};
    const int LOFF[4] = {0, 2, 5, 9};

    if (t < VD) {
        float s = 0.f;
        for (int k = 0; k < 16; ++k) s += ws[OFF_M0P + (b * 16 + k) * VD + t];
        lm[0][t] = s * (1.0f / HW);
    }
    __syncthreads();

    for (int l = 1; l <= 4; ++l) {
        if (t < VD) {
            for (int n = 0; n <= l; ++n) {
                int pl = (n - 1 < 0) ? 0 : (n - 1);
                int pr = (n < l - 1) ? n : (l - 1);
                const float* A = lm[Soff[l - 1] + pl];
                const float* R = lm[Soff[l - 1] + pr];
                bool takeR = false;
                if (pl != pr) {
                    float ln = 0.f, rn = 0.f;
                    for (int k = 0; k < VD; ++k) { ln += A[k] * A[k]; rn += R[k] * R[k]; }
                    takeR = sqrtf(rn) > sqrtf(ln);
                }
                int widx = LOFF[l - 1] + n;
                float s = lb[widx * VD + t];
                for (int k = 0; k < VD; ++k) {
                    float pk = takeR ? R[k] : A[k];
                    s += lw[(widx * VD + t) * VD + k] * pk;
                }
                lm[Soff[l] + n][t] = s;
            }
        }
        __syncthreads();
    }

    if (t == 0) {
        float best = -1.f; int bi = 0;
        for (int n = 0; n < 5; ++n) {
            float s = 0.f;
            for (int k = 0; k < VD; ++k) { float v = lm[10 + n][k]; s += v * v; }
            float lg = sqrtf(s);
            out[b * 5 + n] = lg;                // class_logits
            if (lg > best) { best = lg; bi = n; }
        }
        out[192 + b] = (float)bi;               // selected_class
        int node = bi;
        for (int l = 4; l >= 1; --l) {
            path[l] = LOFF[l - 1] + node;
            int pl = (node - 1 < 0) ? 0 : (node - 1);
            int pr = (node < l - 1) ? node : (l - 1);
            if (pl == pr) node = pl;
            else {
                float ln = 0.f, rn = 0.f;
                for (int k = 0; k < VD; ++k) {
                    float a = lm[Soff[l - 1] + pl][k], r = lm[Soff[l - 1] + pr][k];
                    ln += a * a; rn += r * r;
                }
                node = (sqrtf(rn) > sqrtf(ln)) ? pr : pl;
            }
        }
    }
    __syncthreads();

    // Compose M = W4*W3*W2*W1, c = W4*(W3*(W2*b1+b2)+b3)+b4. Lane j owns column j.
    for (int i = t; i < 256; i += 64) Wst[i] = lw[path[1] * 256 + i];
    __syncthreads();
    float Mc[VD], cc[VD];
    if (t < VD) {
        for (int i = 0; i < VD; ++i) Mc[i] = Wst[i * VD + t];
        for (int i = 0; i < VD; ++i) cc[i] = lb[path[1] * VD + i];
    }
    for (int l = 2; l <= 4; ++l) {
        __syncthreads();
        for (int i = t; i < 256; i += 64) Wst[i] = lw[path[l] * 256 + i];
        __syncthreads();
        if (t < VD) {
            float nM[VD], nc[VD];
            for (int i = 0; i < VD; ++i) {
                float sm = 0.f, sc = 0.f;
                for (int k = 0; k < VD; ++k) {
                    float w = Wst[i * VD + k];
                    sm += w * Mc[k]; sc += w * cc[k];
                }
                nM[i] = sm; nc[i] = sc + lb[path[l] * VD + i];
            }
            for (int i = 0; i < VD; ++i) { Mc[i] = nM[i]; cc[i] = nc[i]; }
        }
    }
    if (t < VD) {
        for (int i = 0; i < VD; ++i) ws[OFF_M + b * 256 + i * VD + t] = Mc[i];
        if (t == 0) for (int i = 0; i < VD; ++i) ws[OFF_C + b * VD + i] = cc[i];
    }
}

// Per-pixel epilogue: f0 = p0+p1; selected = M*f0+c; normalize; m1(relu); m2; block-sum slot.
__global__ __launch_bounds__(256) void k_final(const float* __restrict__ p0,
                                               const float* __restrict__ p1,
                                               const float* __restrict__ Mg,
                                               const float* __restrict__ Cg,
                                               const float* __restrict__ m1w,
                                               const float* __restrict__ m1b,
                                               const float* __restrict__ m2w,
                                               const float* __restrict__ m2b,
                                               float* __restrict__ msp) {
    const int b = blockIdx.y;
    const int t = threadIdx.x;
    __shared__ float sM[256], sc[VD], s1w[1024], s1b[64], s2w[64];
    sM[t] = Mg[b * 256 + t];
    for (int i = t; i < 1024; i += 256) s1w[i] = m1w[i];
    if (t < 64) { s1b[t] = m1b[t]; s2w[t] = m2w[t]; }
    if (t < VD) sc[t] = Cg[b * VD + t];
    __syncthreads();

    const size_t base = (size_t)b * VD * HW + blockIdx.x * 512 + t * 2;
    float2 f[VD];
#pragma unroll
    for (int j = 0; j < VD; ++j) {
        float2 a = *(const float2*)(p0 + base + (size_t)j * HW);
        float2 c = *(const float2*)(p1 + base + (size_t)j * HW);
        f[j].x = a.x + c.x; f[j].y = a.y + c.y;
    }

    float2 v[VD];
#pragma unroll
    for (int i = 0; i < VD; ++i) {
        float2 s; s.x = s.y = sc[i];
#pragma unroll
        for (int j = 0; j < VD; ++j) {
            float w = sM[i * VD + j];
            s.x += w * f[j].x; s.y += w * f[j].y;
        }
        v[i] = s;
    }

    float2 n2; n2.x = n2.y = 0.f;
#pragma unroll
    for (int i = 0; i < VD; ++i) { n2.x += v[i].x * v[i].x; n2.y += v[i].y * v[i].y; }
    float2 inv;
    inv.x = 1.f / (sqrtf(n2.x) + 1e-8f);
    inv.y = 1.f / (sqrtf(n2.y) + 1e-8f);
#pragma unroll
    for (int i = 0; i < VD; ++i) { v[i].x *= inv.x; v[i].y *= inv.y; }

    float mb = m2b[0];
    float2 s2; s2.x = s2.y = mb;
#pragma unroll 8
    for (int o = 0; o < 64; ++o) {
        float2 h; h.x = h.y = s1b[o];
#pragma unroll
        for (int i = 0; i < VD; ++i) {
            float w = s1w[o * VD + i];
            h.x += w * v[i].x; h.y += w * v[i].y;
        }
        h.x = fmaxf(h.x, 0.f); h.y = fmaxf(h.y, 0.f);
        float w2 = s2w[o];
        s2.x += w2 * h.x; s2.y += w2 * h.y;
    }
    float psum = s2.x + s2.y;

    const int lane = t & 63, wv = t >> 6;
#pragma unroll
    for (int off = 32; off > 0; off >>= 1) psum += __shfl_down(psum, off);
    __shared__ float rs[4];
    if (lane == 0) rs[wv] = psum;
    __syncthreads();
    if (t == 0) msp[b * 8 + blockIdx.x] = rs[0] + rs[1] + rs[2] + rs[3];
}

__global__ __launch_bounds__(64) void k_mant(const float* __restrict__ msp,
                                             float* __restrict__ out) {
    int b = threadIdx.x;
    if (b < NB) {
        float m = 0.f;
        for (int k = 0; k < 8; ++k) m += msp[b * 8 + k];
        m *= (1.0f / HW);
        out[160 + b] = (1.0f / (1.0f + expf(-m))) * 0.75f + 0.75f;
    }
}

extern "C" void kernel_launch(void* const* d_in, const int* in_sizes, int n_in,
                              void* d_out, int out_size, void* d_ws, size_t ws_size,
                              hipStream_t stream) {
    const float* feat    = (const float*)d_in[0];
    const float* root_w  = (const float*)d_in[1];
    const float* root_b  = (const float*)d_in[2];
    const float* level_w = (const float*)d_in[3];
    const float* level_b = (const float*)d_in[4];
    const float* m1w     = (const float*)d_in[5];
    const float* m1b     = (const float*)d_in[6];
    const float* m2w     = (const float*)d_in[7];
    const float* m2b     = (const float*)d_in[8];
    float* ws  = (float*)d_ws;
    float* out = (float*)d_out;

    k_root<<<dim3(8, NB, 2), 128, 0, stream>>>(feat, root_w, root_b,
                                               ws + OFF_P0, ws + OFF_M0P);
    k_tree<<<NB, 64, 0, stream>>>(level_w, level_b, ws, out);
    k_final<<<dim3(8, NB), 256, 0, stream>>>(ws + OFF_P0, ws + OFF_P1,
                                             ws + OFF_M, ws + OFF_C,
                                             m1w, m1b, m2w, m2b, ws + OFF_MSP);
    k_mant<<<1, 64, 0, stream>>>(ws + OFF_MSP, out);
}

// Round 4
// 417.580 us; speedup vs baseline: 1.1838x; 1.1838x over previous
//
#include <hip/hip_runtime.h>
#include <math.h>

#define HW 4096
#define NB 32
#define VD 16
#define CPB 128            // channels per k_root block (4-way split)

// ws layout (float offsets) — no zero-init required anywhere
#define OFF_M0P   0        // 32 b * 16 blocks * 16 ch = 8192 per-block partial sums
#define OFF_MSP   8192     // 32 b * 8 blocks = 256 per-block mantissa sums
#define OFF_M     8448     // 32*256 composed path matrices
#define OFF_C     16640    // 32*16 composed path biases
#define OFF_WT    17152    // 512*16 transposed root_w (wt[c][o], c-major)
#define OFF_P     25344    // 4 partial feats0 buffers, each 32*16*4096
#define PSZ       2097152

__global__ __launch_bounds__(256) void k_trans(const float* __restrict__ rw,
                                               float* __restrict__ wt) {
    int i = blockIdx.x * 256 + threadIdx.x;   // 8192 elements
    if (i < 512 * VD) {
        int c = i >> 4, o = i & 15;
        wt[i] = rw[o * 512 + c];
    }
}

// Root conv, channel-split 4-way. 256 thr, 4 px/thread (float4), 128 ch/block.
// Weights: contiguous transposed rows -> wave-uniform s_load from K$.
// Features: explicit register double-buffer so >=4 float4 loads stay in flight.
__global__ __launch_bounds__(256) void k_root(const float* __restrict__ feat,
                                              const float* __restrict__ wt,
                                              const float* __restrict__ rb,
                                              float* __restrict__ pbase,
                                              float* __restrict__ m0p) {
    const int b  = blockIdx.y;
    const int s  = blockIdx.z;
    const int bx = blockIdx.x;
    const int t  = threadIdx.x;
    const int px = bx * 1024 + t * 4;
    const int cb = s * CPB;
    const float* fp = feat + ((size_t)b * 512 + cb) * HW + px;
    const float* wp = wt + (size_t)cb * VD;     // 2048 contiguous floats

    float4 acc[VD];
#pragma unroll
    for (int o = 0; o < VD; ++o) {
        float bb = (s == 0) ? rb[o] : 0.0f;
        acc[o].x = bb; acc[o].y = bb; acc[o].z = bb; acc[o].w = bb;
    }

    float4 cur[4], nxt[4];
#pragma unroll
    for (int k = 0; k < 4; ++k) cur[k] = *(const float4*)(fp + (size_t)k * HW);

    for (int c = 0; c < CPB; c += 4) {
        if (c + 4 < CPB) {
#pragma unroll
            for (int k = 0; k < 4; ++k)
                nxt[k] = *(const float4*)(fp + (size_t)(c + 4 + k) * HW);
        }
        const float* wr = wp + c * VD;          // 64 contiguous floats, uniform
#pragma unroll
        for (int j = 0; j < 4; ++j) {
#pragma unroll
            for (int o = 0; o < VD; ++o) {
                float w = wr[j * VD + o];
                acc[o].x += w * cur[j].x;
                acc[o].y += w * cur[j].y;
                acc[o].z += w * cur[j].z;
                acc[o].w += w * cur[j].w;
            }
        }
#pragma unroll
        for (int k = 0; k < 4; ++k) cur[k] = nxt[k];
    }

    float* op = pbase + (size_t)s * PSZ + (size_t)b * VD * HW + px;
#pragma unroll
    for (int o = 0; o < VD; ++o) *(float4*)(op + (size_t)o * HW) = acc[o];

    __shared__ float red[4][VD];
    const int lane = t & 63, wv = t >> 6;
#pragma unroll
    for (int o = 0; o < VD; ++o) {
        float v = acc[o].x + acc[o].y + acc[o].z + acc[o].w;
#pragma unroll
        for (int off = 32; off > 0; off >>= 1) v += __shfl_down(v, off);
        if (lane == 0) red[wv][o] = v;
    }
    __syncthreads();
    if (t < VD)
        m0p[((b * 4 + s) * 4 + bx) * VD + t] =
            red[0][t] + red[1][t] + red[2][t] + red[3][t];
}

// Tree walk on means: class_logits, selected_class, composed affine map (M,c) per batch.
__global__ __launch_bounds__(64) void k_tree(const float* __restrict__ lw,
                                             const float* __restrict__ lb,
                                             float* __restrict__ ws,
                                             float* __restrict__ out) {
    const int b = blockIdx.x;
    const int t = threadIdx.x;
    __shared__ float lm[15][VD];
    __shared__ float Wst[256];
    __shared__ int   path[5];
    const int Soff[5] = {0, 1, 3, 6, 10};
    const int LOFF[4] = {0, 2, 5, 9};

    if (t < VD) {
        float s = 0.f;
        for (int k = 0; k < 16; ++k) s += ws[OFF_M0P + (b * 16 + k) * VD + t];
        lm[0][t] = s * (1.0f / HW);
    }
    __syncthreads();

    for (int l = 1; l <= 4; ++l) {
        if (t < VD) {
            for (int n = 0; n <= l; ++n) {
                int pl = (n - 1 < 0) ? 0 : (n - 1);
                int pr = (n < l - 1) ? n : (l - 1);
                const float* A = lm[Soff[l - 1] + pl];
                const float* R = lm[Soff[l - 1] + pr];
                bool takeR = false;
                if (pl != pr) {
                    float ln = 0.f, rn = 0.f;
                    for (int k = 0; k < VD; ++k) { ln += A[k] * A[k]; rn += R[k] * R[k]; }
                    takeR = sqrtf(rn) > sqrtf(ln);
                }
                int widx = LOFF[l - 1] + n;
                float s = lb[widx * VD + t];
                for (int k = 0; k < VD; ++k) {
                    float pk = takeR ? R[k] : A[k];
                    s += lw[(widx * VD + t) * VD + k] * pk;
                }
                lm[Soff[l] + n][t] = s;
            }
        }
        __syncthreads();
    }

    if (t == 0) {
        float best = -1.f; int bi = 0;
        for (int n = 0; n < 5; ++n) {
            float s = 0.f;
            for (int k = 0; k < VD; ++k) { float v = lm[10 + n][k]; s += v * v; }
            float lg = sqrtf(s);
            out[b * 5 + n] = lg;                // class_logits
            if (lg > best) { best = lg; bi = n; }
        }
        out[192 + b] = (float)bi;               // selected_class
        int node = bi;
        for (int l = 4; l >= 1; --l) {
            path[l] = LOFF[l - 1] + node;
            int pl = (node - 1 < 0) ? 0 : (node - 1);
            int pr = (node < l - 1) ? node : (l - 1);
            if (pl == pr) node = pl;
            else {
                float ln = 0.f, rn = 0.f;
                for (int k = 0; k < VD; ++k) {
                    float a = lm[Soff[l - 1] + pl][k], r = lm[Soff[l - 1] + pr][k];
                    ln += a * a; rn += r * r;
                }
                node = (sqrtf(rn) > sqrtf(ln)) ? pr : pl;
            }
        }
    }
    __syncthreads();

    for (int i = t; i < 256; i += 64) Wst[i] = lw[path[1] * 256 + i];
    __syncthreads();
    float Mc[VD], cc[VD];
    if (t < VD) {
        for (int i = 0; i < VD; ++i) Mc[i] = Wst[i * VD + t];
        for (int i = 0; i < VD; ++i) cc[i] = lb[path[1] * VD + i];
    }
    for (int l = 2; l <= 4; ++l) {
        __syncthreads();
        for (int i = t; i < 256; i += 64) Wst[i] = lw[path[l] * 256 + i];
        __syncthreads();
        if (t < VD) {
            float nM[VD], nc[VD];
            for (int i = 0; i < VD; ++i) {
                float sm = 0.f, sc = 0.f;
                for (int k = 0; k < VD; ++k) {
                    float w = Wst[i * VD + k];
                    sm += w * Mc[k]; sc += w * cc[k];
                }
                nM[i] = sm; nc[i] = sc + lb[path[l] * VD + i];
            }
            for (int i = 0; i < VD; ++i) { Mc[i] = nM[i]; cc[i] = nc[i]; }
        }
    }
    if (t < VD) {
        for (int i = 0; i < VD; ++i) ws[OFF_M + b * 256 + i * VD + t] = Mc[i];
        if (t == 0) for (int i = 0; i < VD; ++i) ws[OFF_C + b * VD + i] = cc[i];
    }
}

// Epilogue: f0 = sum of 4 partials; M*f0+c; normalize; m1(relu); m2; block-sum slot.
__global__ __launch_bounds__(256) void k_final(const float* __restrict__ pbase,
                                               const float* __restrict__ Mg,
                                               const float* __restrict__ Cg,
                                               const float* __restrict__ m1w,
                                               const float* __restrict__ m1b,
                                               const float* __restrict__ m2w,
                                               const float* __restrict__ m2b,
                                               float* __restrict__ msp) {
    const int b = blockIdx.y;
    const int t = threadIdx.x;
    __shared__ float sM[256], sc[VD], s1w[1024], s1b[64], s2w[64];
    sM[t] = Mg[b * 256 + t];
    for (int i = t; i < 1024; i += 256) s1w[i] = m1w[i];
    if (t < 64) { s1b[t] = m1b[t]; s2w[t] = m2w[t]; }
    if (t < VD) sc[t] = Cg[b * VD + t];
    __syncthreads();

    const size_t base = (size_t)b * VD * HW + blockIdx.x * 512 + t * 2;
    float2 f[VD];
#pragma unroll
    for (int j = 0; j < VD; ++j) {
        float2 a0 = *(const float2*)(pbase + base + (size_t)j * HW);
        float2 a1 = *(const float2*)(pbase + PSZ + base + (size_t)j * HW);
        float2 a2 = *(const float2*)(pbase + 2 * PSZ + base + (size_t)j * HW);
        float2 a3 = *(const float2*)(pbase + 3 * (size_t)PSZ + base + (size_t)j * HW);
        f[j].x = a0.x + a1.x + a2.x + a3.x;
        f[j].y = a0.y + a1.y + a2.y + a3.y;
    }

    float2 v[VD];
#pragma unroll
    for (int i = 0; i < VD; ++i) {
        float2 s; s.x = s.y = sc[i];
#pragma unroll
        for (int j = 0; j < VD; ++j) {
            float w = sM[i * VD + j];
            s.x += w * f[j].x; s.y += w * f[j].y;
        }
        v[i] = s;
    }

    float2 n2; n2.x = n2.y = 0.f;
#pragma unroll
    for (int i = 0; i < VD; ++i) { n2.x += v[i].x * v[i].x; n2.y += v[i].y * v[i].y; }
    float2 inv;
    inv.x = 1.f / (sqrtf(n2.x) + 1e-8f);
    inv.y = 1.f / (sqrtf(n2.y) + 1e-8f);
#pragma unroll
    for (int i = 0; i < VD; ++i) { v[i].x *= inv.x; v[i].y *= inv.y; }

    float mb = m2b[0];
    float2 s2; s2.x = s2.y = mb;
#pragma unroll 8
    for (int o = 0; o < 64; ++o) {
        float2 h; h.x = h.y = s1b[o];
#pragma unroll
        for (int i = 0; i < VD; ++i) {
            float w = s1w[o * VD + i];
            h.x += w * v[i].x; h.y += w * v[i].y;
        }
        h.x = fmaxf(h.x, 0.f); h.y = fmaxf(h.y, 0.f);
        float w2 = s2w[o];
        s2.x += w2 * h.x; s2.y += w2 * h.y;
    }
    float psum = s2.x + s2.y;

    const int lane = t & 63, wv = t >> 6;
#pragma unroll
    for (int off = 32; off > 0; off >>= 1) psum += __shfl_down(psum, off);
    __shared__ float rs[4];
    if (lane == 0) rs[wv] = psum;
    __syncthreads();
    if (t == 0) msp[b * 8 + blockIdx.x] = rs[0] + rs[1] + rs[2] + rs[3];
}

__global__ __launch_bounds__(64) void k_mant(const float* __restrict__ msp,
                                             float* __restrict__ out) {
    int b = threadIdx.x;
    if (b < NB) {
        float m = 0.f;
        for (int k = 0; k < 8; ++k) m += msp[b * 8 + k];
        m *= (1.0f / HW);
        out[160 + b] = (1.0f / (1.0f + expf(-m))) * 0.75f + 0.75f;
    }
}

extern "C" void kernel_launch(void* const* d_in, const int* in_sizes, int n_in,
                              void* d_out, int out_size, void* d_ws, size_t ws_size,
                              hipStream_t stream) {
    const float* feat    = (const float*)d_in[0];
    const float* root_w  = (const float*)d_in[1];
    const float* root_b  = (const float*)d_in[2];
    const float* level_w = (const float*)d_in[3];
    const float* level_b = (const float*)d_in[4];
    const float* m1w     = (const float*)d_in[5];
    const float* m1b     = (const float*)d_in[6];
    const float* m2w     = (const float*)d_in[7];
    const float* m2b     = (const float*)d_in[8];
    float* ws  = (float*)d_ws;
    float* out = (float*)d_out;

    k_trans<<<32, 256, 0, stream>>>(root_w, ws + OFF_WT);
    k_root<<<dim3(4, NB, 4), 256, 0, stream>>>(feat, ws + OFF_WT, root_b,
                                               ws + OFF_P, ws + OFF_M0P);
    k_tree<<<NB, 64, 0, stream>>>(level_w, level_b, ws, out);
    k_final<<<dim3(8, NB), 256, 0, stream>>>(ws + OFF_P, ws + OFF_M, ws + OFF_C,
                                             m1w, m1b, m2w, m2b, ws + OFF_MSP);
    k_mant<<<1, 64, 0, stream>>>(ws + OFF_MSP, out);
}